// Round 10
// baseline (1969.811 us; speedup 1.0000x reference)
//
#include <hip/hip_runtime.h>
#include <hip/hip_bf16.h>

// LSTM: B=1024, SEQ=128, H=1024, NCLS=10, IN_DIM=1.
// PERSISTENT kernel, 4 independent XCD-pair chains (r8/r9 dataflow), r10 K:
//  - Block = 256 batch x 64 gate-cols; B-slice 128 KB LDS-resident (once).
//  - Dual-store epilogue (own h -> own XCD frag-major scratch, plain L2;
//    partner via sc0sc1 MALL staging 256 KB/XCD/step).
//  - r10: K-halves use a SIX-deep register pipeline (p0..p5, 24 KB
//    in-flight/wave — r7/r9's 4-deep 16 KB was the Little's-law limiter at
//    ~3000cy contended L2 latency), per-block kt ROTATION ((i + s&15)&15)
//    to break 32-CU lockstep L2 line contention, and the own-half prologue
//    issues BEFORE pair_poll so the MALL RTT hides under A loads (vmcnt
//    schedule is position-based -> immune to thread0's poll drains).
//  - XCD-local barriers: no-sc global_atomic_add + dual-path sc0/sc0sc1
//    polls (deadlock-proof). One MALL interaction per step.
//  - WAITV carries sched_barrier(0) (rule #18). c-state in registers.
//  - h(127) row-major into Wp region (dead after B init) for logits.
// Barrier state in d_out (zeroed by prepack each launch).

#define HDIM 1024
#define SEQ 128
#define NCLS 10
#define NWG 256

using half8   = __attribute__((ext_vector_type(8))) _Float16;
using floatx4 = __attribute__((ext_vector_type(4))) float;

#define GLOBAL_AS const __attribute__((address_space(1))) void*
#define LDS_AS __attribute__((address_space(3))) void*

#define WAITV(N) do { asm volatile("s_waitcnt vmcnt(" #N ")" ::: "memory");   \
                      __builtin_amdgcn_sched_barrier(0); } while (0)

__device__ __forceinline__ float fast_sig(float x) {
    return __builtin_amdgcn_rcpf(1.f + __expf(-x));
}
__device__ __forceinline__ float fast_tanh(float x) {
    return 1.f - 2.f * __builtin_amdgcn_rcpf(__expf(2.f * x) + 1.f);
}

// System-scope (MALL write-through) fp16 store (r3-proven).
__device__ __forceinline__ void store_h_sys(_Float16* p, float v) {
    union { _Float16 h; unsigned short s; } u;
    u.h = (_Float16)v;
    unsigned int w = u.s;
    asm volatile("global_store_short %0, %1, off sc0 sc1"
                 :: "v"(p), "v"(w) : "memory");
}

// ---------------------------------------------------------------------------
// Prepack fp32->fp16, FRAGMENT-MAJOR 1 KB chunks (proven layout):
// chunk = cg*128 + kt*4 + nt. Lane l: gate = nt, unit j = cg*16 + (l&15),
// k = kt*32 + (l>>4)*8 + i. Block 0 zeroes barrier state in d_out.
// ---------------------------------------------------------------------------
__global__ void prepack_kernel(const float* __restrict__ wgh,
                               const float* __restrict__ wih,
                               const float* __restrict__ wfh,
                               const float* __restrict__ woh,
                               _Float16* __restrict__ Wp,
                               int* __restrict__ bar) {
    if (blockIdx.x == 0) {
        for (int i = threadIdx.x; i < 4096; i += 64) bar[i] = 0;
    }
    const int chunk = blockIdx.x;        // 0..8191
    const int l = threadIdx.x;           // 0..63
    const int cg = chunk >> 7;
    const int rem = chunk & 127;
    const int kt = rem >> 2;
    const int nt = rem & 3;              // = gate
    const int j  = cg * 16 + (l & 15);
    const int k0 = kt * 32 + (l >> 4) * 8;
    const float* src = (nt == 0) ? wgh : (nt == 1) ? wih
                     : (nt == 2) ? wfh : woh;
    src += (size_t)j * HDIM + k0;
    float4 v0 = *(const float4*)(src);
    float4 v1 = *(const float4*)(src + 4);
    union { _Float16 h[8]; uint4 u4; } cv;
    cv.h[0] = (_Float16)v0.x; cv.h[1] = (_Float16)v0.y;
    cv.h[2] = (_Float16)v0.z; cv.h[3] = (_Float16)v0.w;
    cv.h[4] = (_Float16)v1.x; cv.h[5] = (_Float16)v1.y;
    cv.h[6] = (_Float16)v1.z; cv.h[7] = (_Float16)v1.w;
    *(uint4*)(Wp + (size_t)chunk * 512 + l * 8) = cv.u4;
}

// ---------------------------------------------------------------------------
// XCD-local barrier (r9-proven): no-sc atomic add (lands in this XCD's L2)
// + dual-path monotonic poll (sc0 / sc0sc1) -> deadlock-proof.
// ---------------------------------------------------------------------------
__device__ __forceinline__ void l2_bar(int* cnt, int tgt) {
    __syncthreads();
    if (threadIdx.x == 0) {
        int one = 1;
        asm volatile("global_atomic_add %0, %1, off"
                     :: "v"(cnt), "v"(one) : "memory");
        for (;;) {
            int c1, c2;
            asm volatile("global_load_dword %0, %1, off sc0\n\t"
                         "s_waitcnt vmcnt(0)"
                         : "=v"(c1) : "v"(cnt) : "memory");
            if (c1 >= tgt) break;
            asm volatile("global_load_dword %0, %1, off sc0 sc1\n\t"
                         "s_waitcnt vmcnt(0)"
                         : "=v"(c2) : "v"(cnt) : "memory");
            if (c2 >= tgt) break;
            __builtin_amdgcn_s_sleep(1);
        }
    }
    __syncthreads();
    asm volatile("" ::: "memory");
}

// Pair-wide arrival poll (counter at MALL, agent atomics — r7-proven).
__device__ __forceinline__ void pair_poll(int* pc, int tgt) {
    __syncthreads();
    if (threadIdx.x == 0) {
        while (__hip_atomic_load(pc, __ATOMIC_RELAXED,
                                 __HIP_MEMORY_SCOPE_AGENT) < tgt)
            __builtin_amdgcn_s_sleep(1);
    }
    __syncthreads();
    asm volatile("" ::: "memory");
}

struct PParams {
    const _Float16* Wp; _Float16* stg; _Float16* scr; _Float16* hrow;
    const float* x;
    const float* wgx; const float* wix; const float* wfx; const float* wox;
    const float* bg;  const float* bi;  const float* bf;  const float* bo;
    int* bar;
};

// 4 A-fragment register loads for global K-tile kt (1KB-stride imm offsets,
// sc0 = L1 bypass; scratch is written by other CUs on this XCD).
#define LOADA(dst, ktv)                                                       \
    { const _Float16* ap_ = abase + (size_t)(ktv) * 8192;                     \
      asm volatile("global_load_dwordx4 %0, %4, off sc0\n\t"                  \
                   "global_load_dwordx4 %1, %4, off offset:1024 sc0\n\t"      \
                   "global_load_dwordx4 %2, %4, off offset:2048 sc0\n\t"      \
                   "global_load_dwordx4 %3, %4, off offset:3072 sc0"          \
                   : "=v"(dst[0]), "=v"(dst[1]), "=v"(dst[2]), "=v"(dst[3])   \
                   : "v"(ap_) : "memory"); }

// One K-tile of MFMA: 4 B frags from LDS x 4 A frags in regs -> 16 MFMA.
#define MFSTEP(buf, ktg) {                                                    \
    const int bo_ = ((ktg) * 4) * 512 + l * 8;                                \
    half8 b0_ = *(const half8*)(&lB[bo_]);                                    \
    half8 b1_ = *(const half8*)(&lB[bo_ + 512]);                              \
    half8 b2_ = *(const half8*)(&lB[bo_ + 1024]);                             \
    half8 b3_ = *(const half8*)(&lB[bo_ + 1536]);                             \
    _Pragma("unroll")                                                         \
    for (int mt_ = 0; mt_ < 4; ++mt_) {                                       \
        half8 a_ = __builtin_bit_cast(half8, buf[mt_]);                       \
        acc[mt_][0] = __builtin_amdgcn_mfma_f32_16x16x32_f16(a_, b0_, acc[mt_][0], 0, 0, 0); \
        acc[mt_][1] = __builtin_amdgcn_mfma_f32_16x16x32_f16(a_, b1_, acc[mt_][1], 0, 0, 0); \
        acc[mt_][2] = __builtin_amdgcn_mfma_f32_16x16x32_f16(a_, b2_, acc[mt_][2], 0, 0, 0); \
        acc[mt_][3] = __builtin_amdgcn_mfma_f32_16x16x32_f16(a_, b3_, acc[mt_][3], 0, 0, 0); \
    } }

// Rotated kt indices (order-independent accumulation; breaks CU lockstep)
#define OKI(i) (ok + (((i) + rot) & 15))
#define PKI(i) (pk + (((i) + rot) & 15))

// ---------------------------------------------------------------------------
// Persistent LSTM: 256 WGs x 256 thr, 1 WG/CU (forced by 128 KB LDS).
// ---------------------------------------------------------------------------
__global__ __launch_bounds__(256, 1) void lstm_persist(PParams p) {
    __shared__ _Float16 lB[128 * 512];      // 128 KB: B resident (128 frags)

    const float* __restrict__ x = p.x;
    int* bar = p.bar;

    // --- claim (r5-proven): pair = xcc>>1, col-group cg = (xcc&1)*32+s ---
    const unsigned xcc = __builtin_amdgcn_s_getreg(6164) & 7;  // XCC_ID
    int* sl = bar + 2560;
    if (threadIdx.x == 0) {
        int sv = __hip_atomic_fetch_add(&bar[2048 + (int)xcc * 64], 1,
                                        __ATOMIC_RELAXED, __HIP_MEMORY_SCOPE_AGENT);
        sl[blockIdx.x] = sv;
    }
    __syncthreads();
    const int s  = __hip_atomic_load(&sl[blockIdx.x], __ATOMIC_RELAXED,
                                     __HIP_MEMORY_SCOPE_AGENT) & 31;
    const int pr = (int)xcc >> 1;
    const int cg = ((int)xcc & 1) * 32 + s;
    const int b0 = pr * 256;
    const int ok = ((int)xcc & 1) * 16;      // own kt base (cols we produce)
    const int pk = 16 - ok;                  // partner kt base
    const int rot = s & 15;                  // per-block kt rotation phase

    _Float16* scrx  = p.scr + (size_t)xcc * 262144;          // 512 KB scratch
    _Float16* myStgB   = p.stg + (size_t)xcc * 262144;       // 2x256KB parity
    const _Float16* pStgB = p.stg + (size_t)((int)xcc ^ 1) * 262144;

    int* pairc = &bar[pr * 64];
    int* cntB  = &bar[512  + (int)xcc * 64];
    int* flagP = &bar[1024 + (int)xcc * 64];
    int* cntA  = &bar[1536 + (int)xcc * 64];

    const int tid = threadIdx.x;
    const int wv  = tid >> 6;
    const int l   = tid & 63;
    const int lane15 = l & 15;
    const int quad   = l >> 4;

    const int j = cg * 16 + lane15;
    const float wgx_ = p.wgx[j], wix_ = p.wix[j], wfx_ = p.wfx[j], wox_ = p.wox[j];
    const float bg_ = p.bg[j], bi_ = p.bi[j], bf_ = p.bf[j], bo_ = p.bo[j];

    // epilogue scatter constants: element (m,j) -> frag (j>>5)*16 + (m>>4),
    // half-addr within frag = (((j>>3)&3)*16 + (m&15))*8 + (j&7)
    const int lanePart = ((j >> 3) & 3) * 128 + (j & 7);
    const int scrB = ((j >> 5) * 16) * 512 + lanePart;
    const int stgB = (((j >> 5) & 15) * 16) * 512 + lanePart;

    // K-loop A base: frags f = kt*16 + wv*4 + i at f*512 + l*8 halves
    const _Float16* abase = scrx + wv * 2048 + l * 8;

    // --- B init: one linear 128 KB copy into LDS, resident for all steps ---
    #pragma unroll
    for (int i = 0; i < 32; ++i) {
        const int fi = wv * 32 + i;
        __builtin_amdgcn_global_load_lds(
            (GLOBAL_AS)(p.Wp + ((size_t)cg * 128 + fi) * 512 + l * 8),
            (LDS_AS)(&lB[fi * 512]), 16, 0, 0);
    }
    WAITV(0);
    __syncthreads();

    float creg[4][4] = {};   // persistent cell state: 16 f32/lane

    #pragma unroll 1
    for (int t = 0; t < SEQ; ++t) {
        floatx4 acc[4][4] = {};

        if (t > 0) {
            l2_bar(cntB, 32 * t);            // local epi(t-1) -> own half ready

            // ---- own-half prologue ISSUES FIRST (hides pair RTT) ----
            uint4 p0[4], p1[4], p2[4], p3[4], p4[4], p5[4], cv[8];
            LOADA(p0, OKI(0)); LOADA(p1, OKI(1)); LOADA(p2, OKI(2));
            LOADA(p3, OKI(3)); LOADA(p4, OKI(4)); LOADA(p5, OKI(5));

            pair_poll(pairc, 64 * t);        // partner staging(t-1) at MALL

            const _Float16* cb = pStgB + (size_t)((t - 1) & 1) * 131072
                               + (size_t)(s * 8) * 512 + l * 8;
            #pragma unroll
            for (int q = 0; q < 8; ++q) {    // 8 MALL loads, single-output asm
                const _Float16* cq = cb + q * 512;
                asm volatile("global_load_dwordx4 %0, %1, off sc0 sc1"
                             : "=v"(cv[q]) : "v"(cq) : "memory");
            }
            // position-verified vmcnt schedule (6-deep, C injected):
            WAITV(28); MFSTEP(p0, OKI(0));  LOADA(p0, OKI(6));
            WAITV(28); MFSTEP(p1, OKI(1));  LOADA(p1, OKI(7));
            WAITV(28); MFSTEP(p2, OKI(2));  LOADA(p2, OKI(8));
            WAITV(28); MFSTEP(p3, OKI(3));  LOADA(p3, OKI(9));
            WAITV(28); MFSTEP(p4, OKI(4));  LOADA(p4, OKI(10));
            WAITV(28); MFSTEP(p5, OKI(5));  LOADA(p5, OKI(11));
            WAITV(20); MFSTEP(p0, OKI(6));            // forces cv complete
            {   // publish partner frags (plain L2 stores)
                _Float16* db = scrx + (size_t)(pk * 16 + s * 8) * 512 + l * 8;
                #pragma unroll
                for (int q = 0; q < 8; ++q)
                    *(uint4*)(db + q * 512) = cv[q];
            }
            LOADA(p0, OKI(12));
            WAITV(28); MFSTEP(p1, OKI(7));  LOADA(p1, OKI(13));
            WAITV(28); MFSTEP(p2, OKI(8));  LOADA(p2, OKI(14));
            WAITV(28); MFSTEP(p3, OKI(9));  LOADA(p3, OKI(15));
            WAITV(28); MFSTEP(p4, OKI(10));
            WAITV(24); MFSTEP(p5, OKI(11));
            WAITV(12); MFSTEP(p0, OKI(12));           // forces CSTORE retired
            WAITV(8);  MFSTEP(p1, OKI(13));
            WAITV(4);  MFSTEP(p2, OKI(14));
            WAITV(0);  MFSTEP(p3, OKI(15));

            l2_bar(flagP, 32 * t);           // all partner frags materialized

            // ---- partner half (6-deep, rotated) ----
            LOADA(p0, PKI(0)); LOADA(p1, PKI(1)); LOADA(p2, PKI(2));
            LOADA(p3, PKI(3)); LOADA(p4, PKI(4)); LOADA(p5, PKI(5));
            WAITV(20); MFSTEP(p0, PKI(0));  LOADA(p0, PKI(6));
            WAITV(20); MFSTEP(p1, PKI(1));  LOADA(p1, PKI(7));
            WAITV(20); MFSTEP(p2, PKI(2));  LOADA(p2, PKI(8));
            WAITV(20); MFSTEP(p3, PKI(3));  LOADA(p3, PKI(9));
            WAITV(20); MFSTEP(p4, PKI(4));  LOADA(p4, PKI(10));
            WAITV(20); MFSTEP(p5, PKI(5));  LOADA(p5, PKI(11));
            WAITV(20); MFSTEP(p0, PKI(6));  LOADA(p0, PKI(12));
            WAITV(20); MFSTEP(p1, PKI(7));  LOADA(p1, PKI(13));
            WAITV(20); MFSTEP(p2, PKI(8));  LOADA(p2, PKI(14));
            WAITV(20); MFSTEP(p3, PKI(9));  LOADA(p3, PKI(15));
            WAITV(20); MFSTEP(p4, PKI(10));
            WAITV(16); MFSTEP(p5, PKI(11));
            WAITV(12); MFSTEP(p0, PKI(12));
            WAITV(8);  MFSTEP(p1, PKI(13));
            WAITV(4);  MFSTEP(p2, PKI(14));
            WAITV(0);  MFSTEP(p3, PKI(15));
        }

        // x(t) for this lane's 16 batch rows (drains under the cntA barrier)
        float xr[4][4];
        #pragma unroll
        for (int mt = 0; mt < 4; ++mt)
            #pragma unroll
            for (int r = 0; r < 4; ++r) {
                const int m = wv * 64 + mt * 16 + quad * 4 + r;
                xr[mt][r] = x[(size_t)(b0 + m) * SEQ + t];
            }

        l2_bar(cntA, 32 * (t + 1));          // all local K(t) reads done

        // fused LSTM cell epilogue; c in regs. Dual-store h (scratch plain +
        // staging sc0sc1). Last step: row-major for logits.
        _Float16* myStg = myStgB + (size_t)(t & 1) * 131072;
        #pragma unroll
        for (int mt = 0; mt < 4; ++mt) {
            #pragma unroll
            for (int r = 0; r < 4; ++r) {
                const int m = wv * 64 + mt * 16 + quad * 4 + r;
                const float xt = xr[mt][r];
                float pg = acc[mt][0][r] + xt * wgx_ + bg_;
                float pi = acc[mt][1][r] + xt * wix_ + bi_;
                float pf = acc[mt][2][r] + xt * wfx_ + bf_;
                float po = acc[mt][3][r] + xt * wox_ + bo_;
                float gg = fast_tanh(pg);
                float ii = fast_sig(pi);
                float ff = fast_sig(pf);
                float oo = fast_sig(po);
                float cn = gg * ii + creg[mt][r] * ff;
                creg[mt][r] = cn;
                float hv = fast_tanh(cn) * oo;
                if (t < SEQ - 1) {
                    const int off = (wv * 4 + mt) * 512 + (quad * 4 + r) * 8;
                    scrx[scrB + off] = (_Float16)hv;            // plain, L2
                    store_h_sys(&myStg[stgB + off], hv);        // MALL
                } else {
                    p.hrow[(size_t)(b0 + m) * HDIM + j] = (_Float16)hv;
                }
            }
        }
        if (t < SEQ - 1) {
            WAITV(0);                        // h published (L2 + MALL)
            __syncthreads();
            if (threadIdx.x == 0)
                __hip_atomic_fetch_add(pairc, 1, __ATOMIC_RELAXED,
                                       __HIP_MEMORY_SCOPE_AGENT);
        }
    }
}

// ---------------------------------------------------------------------------
// logits = h_last @ w_ph^T + bias_p. One wave per batch row. h(127) is
// row-major in the (dead after init) Wp region; dispatch boundary flushes L2.
// ---------------------------------------------------------------------------
__global__ void logits_kernel(const _Float16* __restrict__ h,
                              const float* __restrict__ wph,
                              const float* __restrict__ bp,
                              float* __restrict__ out) {
    const int w = (blockIdx.x * blockDim.x + threadIdx.x) >> 6; // 0..1023
    const int l = threadIdx.x & 63;
    float accv[NCLS];
    #pragma unroll
    for (int c = 0; c < NCLS; ++c) accv[c] = 0.f;
    for (int k = l; k < HDIM; k += 64) {
        float hv = (float)h[(size_t)w * HDIM + k];
        #pragma unroll
        for (int c = 0; c < NCLS; ++c)
            accv[c] += hv * wph[c * HDIM + k];
    }
    #pragma unroll
    for (int c = 0; c < NCLS; ++c) {
        float v = accv[c];
        #pragma unroll
        for (int off = 32; off > 0; off >>= 1)
            v += __shfl_down(v, off, 64);
        if (l == 0) out[w * NCLS + c] = v + bp[c];
    }
}

extern "C" void kernel_launch(void* const* d_in, const int* in_sizes, int n_in,
                              void* d_out, int out_size, void* d_ws, size_t ws_size,
                              hipStream_t stream) {
    const float* x   = (const float*)d_in[0];
    const float* wgx = (const float*)d_in[1];
    const float* wgh = (const float*)d_in[2];
    const float* wix = (const float*)d_in[3];
    const float* wih = (const float*)d_in[4];
    const float* wfx = (const float*)d_in[5];
    const float* wfh = (const float*)d_in[6];
    const float* wox = (const float*)d_in[7];
    const float* woh = (const float*)d_in[8];
    const float* wph = (const float*)d_in[9];
    const float* bg  = (const float*)d_in[10];
    const float* bi  = (const float*)d_in[11];
    const float* bf  = (const float*)d_in[12];
    const float* bo  = (const float*)d_in[13];
    const float* bp  = (const float*)d_in[14];
    float* out = (float*)d_out;

    char* ws = (char*)d_ws;
    _Float16* Wp  = (_Float16*)(ws);                // 0..8 MB (weights; dead
                                                    // after init -> hrow)
    _Float16* stg = (_Float16*)(ws + (8u << 20));   // 8..12 MB (8x2x256KB)
    _Float16* scr = (_Float16*)(ws + (12u << 20));  // 12..16 MB (8x512KB)
    int*      bar = (int*)d_out;                    // transient barrier state

    prepack_kernel<<<8192, 64, 0, stream>>>(wgh, wih, wfh, woh, Wp, bar);

    PParams pp;
    pp.Wp = Wp; pp.stg = stg; pp.scr = scr; pp.hrow = Wp;
    pp.x = x;
    pp.wgx = wgx; pp.wix = wix; pp.wfx = wfx; pp.wox = wox;
    pp.bg = bg; pp.bi = bi; pp.bf = bf; pp.bo = bo;
    pp.bar = bar;
    lstm_persist<<<NWG, 256, 0, stream>>>(pp);

    logits_kernel<<<256, 256, 0, stream>>>(Wp, wph, bp, out);
}

// Round 13
// 1379.304 us; speedup vs baseline: 1.4281x; 1.4281x over previous
//
#include <hip/hip_runtime.h>
#include <hip/hip_bf16.h>

// LSTM: B=1024, SEQ=128, H=1024, NCLS=10, IN_DIM=1.
// PERSISTENT kernel, 4 independent XCD-pair chains. r13 = r12 resubmitted
// verbatim (r12 bench was an infra failure: container died before running).
// r12 = r11 with the one-line compile fix (spurious cv[q] asm INPUT removed —
// LLVM can't take array-element 'v' inputs; outputs are fine):
//  - Block = 256 batch x 64 gate-cols; B-slice 128 KB LDS-resident (once).
//    XCD pair {2g,2g+1} owns batch-group g; cg=(xcc&1)*32+s via XCC_ID claim.
//  - Step: pair_poll (partner h(t-1) at MALL) -> dedup copy (block s gathers
//    kt=s: 4x16B MALL loads -> 4 plain stores into XCD scratch, frag-major)
//    -> L2-LOCAL barrier arrive (no-sc atomic, ~250cy; r9-proven) ->
//    MFSTEP(kt=s) DIRECTLY from the copy registers (cv[q] IS wave wv's
//    A-fragment q of kt=s; hides barrier poll, skips 1/32 scratch reads) ->
//    poll -> 31-kt FOUR-deep register pipeline (WAITV(12): 3 iterations of
//    L2-latency cover vs r7's 1), kt_i=(s+i)&31.
//  - Epilogue: r7's COALESCED row-major store_h_sys only (r9's frag-major
//    2B/16B-stride scatter caused L2 partial-line RMW + 2x WRITE -> slower).
//    Pair arrive at end of epilogue (publish early, poll late next step).
//  - WAITV carries sched_barrier(0) (rule #18). c-state in registers.
// Barrier state in d_out (zeroed by prepack; logits overwrites at the end).

#define HDIM 1024
#define SEQ 128
#define NCLS 10
#define NWG 256

using half8   = __attribute__((ext_vector_type(8))) _Float16;
using floatx4 = __attribute__((ext_vector_type(4))) float;

#define GLOBAL_AS const __attribute__((address_space(1))) void*
#define LDS_AS __attribute__((address_space(3))) void*

#define WAITV(N) do { asm volatile("s_waitcnt vmcnt(" #N ")" ::: "memory");   \
                      __builtin_amdgcn_sched_barrier(0); } while (0)

__device__ __forceinline__ float fast_sig(float x) {
    return __builtin_amdgcn_rcpf(1.f + __expf(-x));
}
__device__ __forceinline__ float fast_tanh(float x) {
    return 1.f - 2.f * __builtin_amdgcn_rcpf(__expf(2.f * x) + 1.f);
}

// System-scope (MALL write-through) fp16 store (r3-proven).
__device__ __forceinline__ void store_h_sys(_Float16* p, float v) {
    union { _Float16 h; unsigned short s; } u;
    u.h = (_Float16)v;
    unsigned int w = u.s;
    asm volatile("global_store_short %0, %1, off sc0 sc1"
                 :: "v"(p), "v"(w) : "memory");
}

// ---------------------------------------------------------------------------
// Prepack fp32->fp16, FRAGMENT-MAJOR 1 KB chunks (proven layout):
// chunk = cg*128 + kt*4 + nt. Lane l: gate = nt, unit j = cg*16 + (l&15),
// k = kt*32 + (l>>4)*8 + i. Block 0 zeroes barrier state in d_out.
// ---------------------------------------------------------------------------
__global__ void prepack_kernel(const float* __restrict__ wgh,
                               const float* __restrict__ wih,
                               const float* __restrict__ wfh,
                               const float* __restrict__ woh,
                               _Float16* __restrict__ Wp,
                               int* __restrict__ bar) {
    if (blockIdx.x == 0) {
        for (int i = threadIdx.x; i < 4096; i += 64) bar[i] = 0;
    }
    const int chunk = blockIdx.x;        // 0..8191
    const int l = threadIdx.x;           // 0..63
    const int cg = chunk >> 7;
    const int rem = chunk & 127;
    const int kt = rem >> 2;
    const int nt = rem & 3;              // = gate
    const int j  = cg * 16 + (l & 15);
    const int k0 = kt * 32 + (l >> 4) * 8;
    const float* src = (nt == 0) ? wgh : (nt == 1) ? wih
                     : (nt == 2) ? wfh : woh;
    src += (size_t)j * HDIM + k0;
    float4 v0 = *(const float4*)(src);
    float4 v1 = *(const float4*)(src + 4);
    union { _Float16 h[8]; uint4 u4; } cv;
    cv.h[0] = (_Float16)v0.x; cv.h[1] = (_Float16)v0.y;
    cv.h[2] = (_Float16)v0.z; cv.h[3] = (_Float16)v0.w;
    cv.h[4] = (_Float16)v1.x; cv.h[5] = (_Float16)v1.y;
    cv.h[6] = (_Float16)v1.z; cv.h[7] = (_Float16)v1.w;
    *(uint4*)(Wp + (size_t)chunk * 512 + l * 8) = cv.u4;
}

// Pair-wide arrival poll (counter at MALL, agent atomics — r7-proven).
__device__ __forceinline__ void pair_poll(int* pc, int tgt) {
    __syncthreads();
    if (threadIdx.x == 0) {
        while (__hip_atomic_load(pc, __ATOMIC_RELAXED,
                                 __HIP_MEMORY_SCOPE_AGENT) < tgt)
            __builtin_amdgcn_s_sleep(1);
    }
    __syncthreads();
    asm volatile("" ::: "memory");
}

struct PParams {
    const _Float16* Wp; _Float16* hb0; _Float16* hb1; _Float16* scr;
    const float* x;
    const float* wgx; const float* wix; const float* wfx; const float* wox;
    const float* bg;  const float* bi;  const float* bf;  const float* bo;
    int* bar;
};

// 4 A-fragment register loads for global K-tile kt (1KB-stride imm offsets,
// sc0 = L1 bypass; scratch is written by other CUs on this XCD).
#define LOADA(dst, ktv)                                                       \
    { const _Float16* ap_ = abase + (size_t)(ktv) * 8192;                     \
      asm volatile("global_load_dwordx4 %0, %4, off sc0\n\t"                  \
                   "global_load_dwordx4 %1, %4, off offset:1024 sc0\n\t"      \
                   "global_load_dwordx4 %2, %4, off offset:2048 sc0\n\t"      \
                   "global_load_dwordx4 %3, %4, off offset:3072 sc0"          \
                   : "=v"(dst[0]), "=v"(dst[1]), "=v"(dst[2]), "=v"(dst[3])   \
                   : "v"(ap_) : "memory"); }

// One K-tile of MFMA: 4 B frags from LDS x 4 A frags in regs -> 16 MFMA.
#define MFSTEP(buf, ktg) {                                                    \
    const int bo_ = ((ktg) * 4) * 512 + l * 8;                                \
    half8 b0_ = *(const half8*)(&lB[bo_]);                                    \
    half8 b1_ = *(const half8*)(&lB[bo_ + 512]);                              \
    half8 b2_ = *(const half8*)(&lB[bo_ + 1024]);                             \
    half8 b3_ = *(const half8*)(&lB[bo_ + 1536]);                             \
    _Pragma("unroll")                                                         \
    for (int mt_ = 0; mt_ < 4; ++mt_) {                                       \
        half8 a_ = __builtin_bit_cast(half8, buf[mt_]);                       \
        acc[mt_][0] = __builtin_amdgcn_mfma_f32_16x16x32_f16(a_, b0_, acc[mt_][0], 0, 0, 0); \
        acc[mt_][1] = __builtin_amdgcn_mfma_f32_16x16x32_f16(a_, b1_, acc[mt_][1], 0, 0, 0); \
        acc[mt_][2] = __builtin_amdgcn_mfma_f32_16x16x32_f16(a_, b2_, acc[mt_][2], 0, 0, 0); \
        acc[mt_][3] = __builtin_amdgcn_mfma_f32_16x16x32_f16(a_, b3_, acc[mt_][3], 0, 0, 0); \
    } }

#define KI(i) ((s + (i)) & 31)

// ---------------------------------------------------------------------------
// Persistent LSTM: 256 WGs x 256 thr, 1 WG/CU (forced by 128 KB LDS).
// Block = 256 batch x 64 cols; wave wv owns rows [wv*64, wv*64+64).
// ---------------------------------------------------------------------------
__global__ __launch_bounds__(256, 1) void lstm_persist(PParams p) {
    __shared__ _Float16 lB[128 * 512];      // 128 KB: B resident (128 frags)

    const float* __restrict__ x = p.x;
    int* bar = p.bar;

    // --- claim (r5-proven): pair = xcc>>1, col-group cg = (xcc&1)*32+s ---
    const unsigned xcc = __builtin_amdgcn_s_getreg(6164) & 7;  // XCC_ID
    int* sl = bar + 2560;
    if (threadIdx.x == 0) {
        int sv = __hip_atomic_fetch_add(&bar[2048 + (int)xcc * 64], 1,
                                        __ATOMIC_RELAXED, __HIP_MEMORY_SCOPE_AGENT);
        sl[blockIdx.x] = sv;
    }
    __syncthreads();
    const int s  = __hip_atomic_load(&sl[blockIdx.x], __ATOMIC_RELAXED,
                                     __HIP_MEMORY_SCOPE_AGENT) & 31;
    const int pr = (int)xcc >> 1;            // pair id = batch group
    const int cg = ((int)xcc & 1) * 32 + s;
    const int b0 = pr * 256;
    _Float16* scrx = p.scr + (size_t)xcc * 262144;   // 512 KB per XCD

    int* pairc = &bar[pr * 64];
    int* cntX  = &bar[512 + (int)xcc * 64];

    const int tid = threadIdx.x;
    const int wv  = tid >> 6;                // wave = row-group (4 x 64 rows)
    const int l   = tid & 63;
    const int lane15 = l & 15;
    const int quad   = l >> 4;

    // lane's unit j; epilogue constants (hoisted once for all steps)
    const int j = cg * 16 + lane15;
    const float wgx_ = p.wgx[j], wix_ = p.wix[j], wfx_ = p.wfx[j], wox_ = p.wox[j];
    const float bg_ = p.bg[j], bi_ = p.bi[j], bf_ = p.bf[j], bo_ = p.bo[j];

    // K-loop A base: frag f = kt*16 + wv*4 + i at f*512 + l*8 halves
    const _Float16* abase = scrx + wv * 2048 + l * 8;

    // --- B init: one linear 128 KB copy into LDS, resident for all steps ---
    #pragma unroll
    for (int i = 0; i < 32; ++i) {
        const int fi = wv * 32 + i;
        __builtin_amdgcn_global_load_lds(
            (GLOBAL_AS)(p.Wp + ((size_t)cg * 128 + fi) * 512 + l * 8),
            (LDS_AS)(&lB[fi * 512]), 16, 0, 0);
    }
    WAITV(0);
    __syncthreads();

    float creg[4][4] = {};   // persistent cell state: 16 f32/lane

    #pragma unroll 1
    for (int t = 0; t < SEQ; ++t) {
        const _Float16* h_in  = (t & 1) ? p.hb0 : p.hb1;
        _Float16*       h_out = (t & 1) ? p.hb1 : p.hb0;

        // x(t) for this lane's 16 batch rows (drains under copy's WAITV(0))
        float xr[4][4];
        #pragma unroll
        for (int mt = 0; mt < 4; ++mt)
            #pragma unroll
            for (int r = 0; r < 4; ++r) {
                const int m = wv * 64 + mt * 16 + quad * 4 + r;
                xr[mt][r] = x[(size_t)(b0 + m) * SEQ + t];
            }

        floatx4 acc[4][4] = {};

        if (t > 0) {
            pair_poll(pairc, 64 * t);        // pair h(t-1) drained to MALL

            // ---- dedup copy: block s gathers kt=s (4x16B MALL loads).
            // cv[q] IS wave wv's A-fragment q of kt=s (frag f=s*16+wv*4+q:
            // row = b0+(f&15)*16+lane15, k = s*32+quad*8, 8 halves).
            uint4 cv[4];
            #pragma unroll
            for (int q = 0; q < 4; ++q) {
                const int f   = s * 16 + wv * 4 + q;
                const int row = b0 + (f & 15) * 16 + lane15;
                const int k0  = (f >> 4) * 32 + quad * 8;
                const _Float16* srcp = h_in + (size_t)row * HDIM + k0;
                asm volatile("global_load_dwordx4 %0, %1, off sc0 sc1"
                             : "=v"(cv[q]) : "v"(srcp) : "memory");
            }
            WAITV(0);
            #pragma unroll
            for (int q = 0; q < 4; ++q) {
                const int f = s * 16 + wv * 4 + q;
                *(uint4*)(scrx + (size_t)f * 512 + l * 8) = cv[q];
            }
            WAITV(0);                        // scratch stores retired in L2
            __syncthreads();                 // whole block's stores done

            // ---- L2-local barrier arrive (no-sc atomic, r9-proven path) ---
            if (tid == 0) {
                int one = 1;
                asm volatile("global_atomic_add %0, %1, off"
                             :: "v"(cntX), "v"(one) : "memory");
            }

            MFSTEP(cv, s);                   // kt=s direct from copy regs

            // ---- poll (dual-path sc0 / sc0sc1 -> deadlock-proof) ----
            if (tid == 0) {
                const int tgt = 32 * t;
                for (;;) {
                    int c1, c2;
                    asm volatile("global_load_dword %0, %1, off sc0\n\t"
                                 "s_waitcnt vmcnt(0)"
                                 : "=v"(c1) : "v"(cntX) : "memory");
                    if (c1 >= tgt) break;
                    asm volatile("global_load_dword %0, %1, off sc0 sc1\n\t"
                                 "s_waitcnt vmcnt(0)"
                                 : "=v"(c2) : "v"(cntX) : "memory");
                    if (c2 >= tgt) break;
                    __builtin_amdgcn_s_sleep(1);
                }
            }
            __syncthreads();
            __builtin_amdgcn_sched_barrier(0);

            // ---- 31 remaining kt, 4-deep register pipeline, kt=(s+i)&31 ---
            uint4 pa[4], pb[4], pc_[4], pd[4];
            LOADA(pa, KI(1)); LOADA(pb, KI(2)); LOADA(pc_, KI(3)); LOADA(pd, KI(4));
            WAITV(12); MFSTEP(pa, KI(1));   LOADA(pa, KI(5));
            WAITV(12); MFSTEP(pb, KI(2));   LOADA(pb, KI(6));
            WAITV(12); MFSTEP(pc_, KI(3));  LOADA(pc_, KI(7));
            WAITV(12); MFSTEP(pd, KI(4));   LOADA(pd, KI(8));
            WAITV(12); MFSTEP(pa, KI(5));   LOADA(pa, KI(9));
            WAITV(12); MFSTEP(pb, KI(6));   LOADA(pb, KI(10));
            WAITV(12); MFSTEP(pc_, KI(7));  LOADA(pc_, KI(11));
            WAITV(12); MFSTEP(pd, KI(8));   LOADA(pd, KI(12));
            WAITV(12); MFSTEP(pa, KI(9));   LOADA(pa, KI(13));
            WAITV(12); MFSTEP(pb, KI(10));  LOADA(pb, KI(14));
            WAITV(12); MFSTEP(pc_, KI(11)); LOADA(pc_, KI(15));
            WAITV(12); MFSTEP(pd, KI(12));  LOADA(pd, KI(16));
            WAITV(12); MFSTEP(pa, KI(13));  LOADA(pa, KI(17));
            WAITV(12); MFSTEP(pb, KI(14));  LOADA(pb, KI(18));
            WAITV(12); MFSTEP(pc_, KI(15)); LOADA(pc_, KI(19));
            WAITV(12); MFSTEP(pd, KI(16));  LOADA(pd, KI(20));
            WAITV(12); MFSTEP(pa, KI(17));  LOADA(pa, KI(21));
            WAITV(12); MFSTEP(pb, KI(18));  LOADA(pb, KI(22));
            WAITV(12); MFSTEP(pc_, KI(19)); LOADA(pc_, KI(23));
            WAITV(12); MFSTEP(pd, KI(20));  LOADA(pd, KI(24));
            WAITV(12); MFSTEP(pa, KI(21));  LOADA(pa, KI(25));
            WAITV(12); MFSTEP(pb, KI(22));  LOADA(pb, KI(26));
            WAITV(12); MFSTEP(pc_, KI(23)); LOADA(pc_, KI(27));
            WAITV(12); MFSTEP(pd, KI(24));  LOADA(pd, KI(28));
            WAITV(12); MFSTEP(pa, KI(25));  LOADA(pa, KI(29));
            WAITV(12); MFSTEP(pb, KI(26));  LOADA(pb, KI(30));
            WAITV(12); MFSTEP(pc_, KI(27)); LOADA(pc_, KI(31));
            WAITV(12); MFSTEP(pd, KI(28));
            WAITV(8);  MFSTEP(pa, KI(29));
            WAITV(4);  MFSTEP(pb, KI(30));
            WAITV(0);  MFSTEP(pc_, KI(31));
        }

        // fused LSTM cell epilogue: lane holds 4 gates (nt) of (batch m,
        // unit j); c in regs; COALESCED row-major h store (32B runs).
        #pragma unroll
        for (int mt = 0; mt < 4; ++mt) {
            #pragma unroll
            for (int r = 0; r < 4; ++r) {
                const int m = wv * 64 + mt * 16 + quad * 4 + r;
                const float xt = xr[mt][r];
                float pg = acc[mt][0][r] + xt * wgx_ + bg_;
                float pi = acc[mt][1][r] + xt * wix_ + bi_;
                float pf = acc[mt][2][r] + xt * wfx_ + bf_;
                float po = acc[mt][3][r] + xt * wox_ + bo_;
                float gg = fast_tanh(pg);
                float ii = fast_sig(pi);
                float ff = fast_sig(pf);
                float oo = fast_sig(po);
                float cn = gg * ii + creg[mt][r] * ff;
                creg[mt][r] = cn;
                store_h_sys(&h_out[(size_t)(b0 + m) * HDIM + j],
                            fast_tanh(cn) * oo);
            }
        }
        if (t < SEQ - 1) {
            WAITV(0);                        // h(t) drained to MALL
            __syncthreads();                 // all waves drained
            if (tid == 0)                    // publish early (poll next step)
                __hip_atomic_fetch_add(pairc, 1, __ATOMIC_RELAXED,
                                       __HIP_MEMORY_SCOPE_AGENT);
        }
    }
}

// ---------------------------------------------------------------------------
// logits = h_last @ w_ph^T + bias_p. One wave per batch row. h(127) is in
// MALL via sc0sc1 stores; dispatch boundary makes it visible. Overwrites
// the transient barrier state in d_out.
// ---------------------------------------------------------------------------
__global__ void logits_kernel(const _Float16* __restrict__ h,
                              const float* __restrict__ wph,
                              const float* __restrict__ bp,
                              float* __restrict__ out) {
    const int w = (blockIdx.x * blockDim.x + threadIdx.x) >> 6; // 0..1023
    const int l = threadIdx.x & 63;
    float accv[NCLS];
    #pragma unroll
    for (int c = 0; c < NCLS; ++c) accv[c] = 0.f;
    for (int k = l; k < HDIM; k += 64) {
        float hv = (float)h[(size_t)w * HDIM + k];
        #pragma unroll
        for (int c = 0; c < NCLS; ++c)
            accv[c] += hv * wph[c * HDIM + k];
    }
    #pragma unroll
    for (int c = 0; c < NCLS; ++c) {
        float v = accv[c];
        #pragma unroll
        for (int off = 32; off > 0; off >>= 1)
            v += __shfl_down(v, off, 64);
        if (l == 0) out[w * NCLS + c] = v + bp[c];
    }
}

extern "C" void kernel_launch(void* const* d_in, const int* in_sizes, int n_in,
                              void* d_out, int out_size, void* d_ws, size_t ws_size,
                              hipStream_t stream) {
    const float* x   = (const float*)d_in[0];
    const float* wgx = (const float*)d_in[1];
    const float* wgh = (const float*)d_in[2];
    const float* wix = (const float*)d_in[3];
    const float* wih = (const float*)d_in[4];
    const float* wfx = (const float*)d_in[5];
    const float* wfh = (const float*)d_in[6];
    const float* wox = (const float*)d_in[7];
    const float* woh = (const float*)d_in[8];
    const float* wph = (const float*)d_in[9];
    const float* bg  = (const float*)d_in[10];
    const float* bi  = (const float*)d_in[11];
    const float* bf  = (const float*)d_in[12];
    const float* bo  = (const float*)d_in[13];
    const float* bp  = (const float*)d_in[14];
    float* out = (float*)d_out;

    char* ws = (char*)d_ws;
    _Float16* Wp    = (_Float16*)(ws);               // 0..8 MB (8192 x 1KB)
    _Float16* hbuf0 = (_Float16*)(ws + (8u << 20));  // 8..10 MB
    _Float16* hbuf1 = (_Float16*)(ws + (10u << 20)); // 10..12 MB
    _Float16* scr   = (_Float16*)(ws + (12u << 20)); // 12..16 MB (8 x 512 KB)
    int*      bar   = (int*)d_out;                   // transient barrier state

    prepack_kernel<<<8192, 64, 0, stream>>>(wgh, wih, wfh, woh, Wp, bar);

    PParams pp;
    pp.Wp = Wp; pp.hb0 = hbuf0; pp.hb1 = hbuf1; pp.scr = scr;
    pp.x = x;
    pp.wgx = wgx; pp.wix = wix; pp.wfx = wfx; pp.wox = wox;
    pp.bg = bg; pp.bi = bi; pp.bf = bf; pp.bo = bo;
    pp.bar = bar;
    lstm_persist<<<NWG, 256, 0, stream>>>(pp);

    logits_kernel<<<256, 256, 0, stream>>>(hbuf1, wph, bp, out);  // t=127 -> hbuf1
}